// Round 2
// baseline (241.734 us; speedup 1.0000x reference)
//
#include <hip/hip_runtime.h>
#include <hip/hip_bf16.h>

#define B 512
#define N 1024
#define D 1024
#define FUSE 1024
#define A 256

typedef float f32x4 __attribute__((ext_vector_type(4)));

__device__ __forceinline__ float fast_exp2(float x) { return __builtin_amdgcn_exp2f(x); }
__device__ __forceinline__ float fast_rcp(float x)  { return __builtin_amdgcn_rcpf(x); }

static constexpr float TANH_C = 2.8853900817779268f; // 2*log2(e)
static constexpr float LOG2E  = 1.4426950408889634f;

// ---------------------------------------------------------------------------
// Kernel 1: q = fuse_rep @ Wq (prescaled by 2*log2e), k = conf @ Wk (prescaled)
// 8 rows per block, input rows staged in LDS (broadcast reads), W streamed.
// ---------------------------------------------------------------------------
__global__ __launch_bounds__(256) void qk_kernel(
    const float* __restrict__ fuse_rep, const float* __restrict__ conf,
    const float* __restrict__ Wq, const float* __restrict__ Wk,
    float* __restrict__ qbuf, float* __restrict__ kbuf)
{
    __shared__ float rows[8 * 1024];
    const int blk = blockIdx.x;
    const int tid = threadIdx.x;

    const float* src;
    const float* W;
    float* dst;
    if (blk < B / 8) {
        int row0 = blk * 8;
        src = fuse_rep + (size_t)row0 * FUSE;
        W = Wq;
        dst = qbuf + (size_t)row0 * A;
    } else {
        int row0 = (blk - B / 8) * 8;
        src = conf + (size_t)row0 * D;
        W = Wk;
        dst = kbuf + (size_t)row0 * A;
    }

    const f32x4* src4 = (const f32x4*)src;
    f32x4* rows4 = (f32x4*)rows;
#pragma unroll
    for (int j = 0; j < 8; ++j) rows4[tid + j * 256] = src4[tid + j * 256];
    __syncthreads();

    float acc[8] = {};
#pragma unroll 4
    for (int f = 0; f < 1024; ++f) {
        float wv = W[(size_t)f * A + tid];
#pragma unroll
        for (int j = 0; j < 8; ++j) acc[j] += rows[j * 1024 + f] * wv;
    }
#pragma unroll
    for (int j = 0; j < 8; ++j) dst[(size_t)j * A + tid] = acc[j] * TANH_C;
}

// ---------------------------------------------------------------------------
// Kernel 2: s[b,n] = -2 * sum_a wt[a] * rcp(exp2(q'[b,a]+k'[n,a]) + 1)
// (softmax-shift-equivalent to sum_a wt[a]*tanh(q+k))
// 32x32 (b,n) tile per block; q-tile linear LDS (broadcast reads),
// k-tile XOR-swizzled LDS (conflict-mitigated ds_read_b128).
// ---------------------------------------------------------------------------
__global__ __launch_bounds__(256) void scores_kernel(
    const float* __restrict__ qbuf, const float* __restrict__ kbuf,
    const float* __restrict__ wt, float* __restrict__ s)
{
    __shared__ f32x4 qs[32 * 64];
    __shared__ f32x4 ks[32 * 64];
    const int tid = threadIdx.x;
    const int b0 = blockIdx.x * 32;
    const int n0 = blockIdx.y * 32;

    const f32x4* q4 = (const f32x4*)qbuf + (size_t)b0 * 64;
    const f32x4* k4 = (const f32x4*)kbuf + (size_t)n0 * 64;
#pragma unroll
    for (int j = 0; j < 8; ++j) {
        int idx = tid + j * 256;
        int r = idx >> 6, c = idx & 63;
        qs[idx] = q4[idx];
        ks[r * 64 + (c ^ (r & 15))] = k4[idx];
    }
    __syncthreads();

    const int bl = tid >> 5;   // 0..7
    const int nl = tid & 31;   // 0..31
    const f32x4* wt4 = (const f32x4*)wt;

    float acc0 = 0.f, acc1 = 0.f, acc2 = 0.f, acc3 = 0.f;
    for (int a4 = 0; a4 < 64; ++a4) {
        f32x4 kv = ks[nl * 64 + (a4 ^ (nl & 15))];
        f32x4 wv = wt4[a4];
        f32x4 q0 = qs[(bl) * 64 + a4];
        f32x4 q1 = qs[(bl + 8) * 64 + a4];
        f32x4 q2 = qs[(bl + 16) * 64 + a4];
        f32x4 q3 = qs[(bl + 24) * 64 + a4];
#pragma unroll
        for (int c = 0; c < 4; ++c) {
            float kc = kv[c], wc = wv[c];
            acc0 += wc * fast_rcp(fast_exp2(q0[c] + kc) + 1.0f);
            acc1 += wc * fast_rcp(fast_exp2(q1[c] + kc) + 1.0f);
            acc2 += wc * fast_rcp(fast_exp2(q2[c] + kc) + 1.0f);
            acc3 += wc * fast_rcp(fast_exp2(q3[c] + kc) + 1.0f);
        }
    }
    s[(size_t)(b0 + bl) * N + n0 + nl]      = -2.0f * acc0;
    s[(size_t)(b0 + bl + 8) * N + n0 + nl]  = -2.0f * acc1;
    s[(size_t)(b0 + bl + 16) * N + n0 + nl] = -2.0f * acc2;
    s[(size_t)(b0 + bl + 24) * N + n0 + nl] = -2.0f * acc3;
}

// ---------------------------------------------------------------------------
// Kernel 3: row softmax over N, times probs[n], in-place on s.
// ---------------------------------------------------------------------------
__global__ __launch_bounds__(256) void softmax_kernel(
    float* __restrict__ s, const float* __restrict__ probs)
{
    const int b = blockIdx.x, tid = threadIdx.x;
    f32x4* s4 = (f32x4*)(s + (size_t)b * N);
    f32x4 v = s4[tid];

    float m = fmaxf(fmaxf(v[0], v[1]), fmaxf(v[2], v[3]));
    for (int off = 32; off > 0; off >>= 1) m = fmaxf(m, __shfl_xor(m, off));
    __shared__ float redm[4];
    __shared__ float reds[4];
    const int wid = tid >> 6, lane = tid & 63;
    if (lane == 0) redm[wid] = m;
    __syncthreads();
    m = fmaxf(fmaxf(redm[0], redm[1]), fmaxf(redm[2], redm[3]));

    f32x4 e;
#pragma unroll
    for (int c = 0; c < 4; ++c) e[c] = fast_exp2((v[c] - m) * LOG2E);
    float sum = e[0] + e[1] + e[2] + e[3];
    for (int off = 32; off > 0; off >>= 1) sum += __shfl_xor(sum, off);
    if (lane == 0) reds[wid] = sum;
    __syncthreads();
    sum = reds[0] + reds[1] + reds[2] + reds[3];

    const float inv = fast_rcp(sum);
    const f32x4* p4 = (const f32x4*)probs;
    f32x4 p = p4[tid];
#pragma unroll
    for (int c = 0; c < 4; ++c) v[c] = e[c] * inv * p[c];
    s4[tid] = v;
}

// ---------------------------------------------------------------------------
// Kernel 4: fin[b,d] = sum_n w[b,n] * conf[n,d]   (fp32 tiled GEMM)
// 64(b) x 64(d) tile per block, K-chunk 16; w-tile padded [64][17].
// ---------------------------------------------------------------------------
__global__ __launch_bounds__(256) void fin_kernel(
    const float* __restrict__ w, const float* __restrict__ conf,
    float* __restrict__ out)
{
    __shared__ float ws[64 * 17];
    __shared__ f32x4 cs[16 * 16];
    const int tid = threadIdx.x;
    const int tx = tid & 15, ty = tid >> 4;
    const int d0 = blockIdx.x * 64, b0 = blockIdx.y * 64;

    const f32x4* w4 = (const f32x4*)w;
    const f32x4* c4 = (const f32x4*)conf;
    f32x4 acc[4] = {};

    for (int kk = 0; kk < N; kk += 16) {
        {
            int r = tid >> 2, cq = tid & 3;
            f32x4 val = w4[(size_t)(b0 + r) * (N / 4) + (kk >> 2) + cq];
#pragma unroll
            for (int t = 0; t < 4; ++t) ws[r * 17 + cq * 4 + t] = val[t];
            int r2 = tid >> 4, c2 = tid & 15;
            cs[r2 * 16 + c2] = c4[(size_t)(kk + r2) * (D / 4) + (d0 >> 2) + c2];
        }
        __syncthreads();
#pragma unroll
        for (int k = 0; k < 16; ++k) {
            f32x4 bv = cs[k * 16 + tx];
            float a0 = ws[(ty) * 17 + k];
            float a1 = ws[(ty + 16) * 17 + k];
            float a2 = ws[(ty + 32) * 17 + k];
            float a3 = ws[(ty + 48) * 17 + k];
#pragma unroll
            for (int c = 0; c < 4; ++c) {
                acc[0][c] += a0 * bv[c];
                acc[1][c] += a1 * bv[c];
                acc[2][c] += a2 * bv[c];
                acc[3][c] += a3 * bv[c];
            }
        }
        __syncthreads();
    }
#pragma unroll
    for (int i = 0; i < 4; ++i) {
        f32x4* o4 = (f32x4*)(out + (size_t)(b0 + ty + 16 * i) * D + d0);
        o4[tx] = acc[i];
    }
}

// ---------------------------------------------------------------------------
extern "C" void kernel_launch(void* const* d_in, const int* in_sizes, int n_in,
                              void* d_out, int out_size, void* d_ws, size_t ws_size,
                              hipStream_t stream) {
    const float* conf     = (const float*)d_in[0]; // [N,D]
    const float* fuse_rep = (const float*)d_in[1]; // [B,FUSE]
    const float* probs    = (const float*)d_in[2]; // [1,N]
    const float* Wq       = (const float*)d_in[3]; // [FUSE,A]
    const float* Wk       = (const float*)d_in[4]; // [D,A]
    const float* wt       = (const float*)d_in[5]; // [A]
    float* out = (float*)d_out;                    // [B,D]

    float* qbuf = (float*)d_ws;                    // B*A
    float* kbuf = qbuf + (size_t)B * A;            // N*A
    float* sbuf = kbuf + (size_t)N * A;            // B*N

    hipLaunchKernelGGL(qk_kernel, dim3((B + N) / 8), dim3(256), 0, stream,
                       fuse_rep, conf, Wq, Wk, qbuf, kbuf);
    hipLaunchKernelGGL(scores_kernel, dim3(B / 32, N / 32), dim3(256), 0, stream,
                       qbuf, kbuf, wt, sbuf);
    hipLaunchKernelGGL(softmax_kernel, dim3(B), dim3(256), 0, stream,
                       sbuf, probs);
    hipLaunchKernelGGL(fin_kernel, dim3(D / 64, B / 64), dim3(256), 0, stream,
                       sbuf, conf, out);
}

// Round 3
// 123.524 us; speedup vs baseline: 1.9570x; 1.9570x over previous
//
#include <hip/hip_runtime.h>
#include <hip/hip_bf16.h>

#define B 512
#define N 1024
#define D 1024
#define FUSE 1024
#define A 256

typedef float f32x4 __attribute__((ext_vector_type(4)));
typedef short bf16x8 __attribute__((ext_vector_type(8)));
typedef unsigned short u16x4 __attribute__((ext_vector_type(4)));

__device__ __forceinline__ float fast_exp2(float x) { return __builtin_amdgcn_exp2f(x); }
__device__ __forceinline__ float fast_rcp(float x)  { return __builtin_amdgcn_rcpf(x); }

static constexpr float TANH_C = 2.8853900817779268f; // 2*log2(e)
static constexpr float LOG2E  = 1.4426950408889634f;

__device__ __forceinline__ unsigned short f2bf(float x) {
    __hip_bfloat16 h = __float2bfloat16(x);
    return *reinterpret_cast<unsigned short*>(&h);
}

// ---------------------------------------------------------------------------
// Kernel 0: cast inputs to bf16. Straight: fuse_rep, conf. Transposed (so the
// GEMM B-operand is K-contiguous): conf^T, (Wq*TANH_C)^T, (Wk*TANH_C)^T.
// 64x64 f32 tile per block; transpose via padded LDS tile.
// ---------------------------------------------------------------------------
__global__ __launch_bounds__(256) void cast_kernel(
    const float* __restrict__ fuse, const float* __restrict__ conf,
    const float* __restrict__ Wq, const float* __restrict__ Wk,
    short* __restrict__ fuse_bf, short* __restrict__ conf_bf,
    short* __restrict__ confT, short* __restrict__ WqT, short* __restrict__ WkT)
{
    __shared__ float tile[64 * 65];
    int bid = blockIdx.x;
    const float* src; short* dstS = nullptr; short* dstT = nullptr;
    int r0, c0, spitch; float scale = 1.0f;
    if (bid < 128) {                 // fuse straight: 8 x 16 tiles
        src = fuse; dstS = fuse_bf; spitch = FUSE;
        r0 = (bid >> 4) * 64; c0 = (bid & 15) * 64;
    } else if (bid < 384) {          // conf straight + transposed: 16 x 16
        int b = bid - 128; src = conf; dstS = conf_bf; dstT = confT; spitch = D;
        r0 = (b >> 4) * 64; c0 = (b & 15) * 64;
    } else if (bid < 448) {          // Wq transposed: src [1024][256], 16 x 4
        int b = bid - 384; src = Wq; dstT = WqT; spitch = A; scale = TANH_C;
        r0 = (b >> 2) * 64; c0 = (b & 3) * 64;
    } else {                         // Wk transposed
        int b = bid - 448; src = Wk; dstT = WkT; spitch = A; scale = TANH_C;
        r0 = (b >> 2) * 64; c0 = (b & 3) * 64;
    }
    const int tr = threadIdx.x >> 4, tc = (threadIdx.x & 15) * 4;

    f32x4 v[4];
#pragma unroll
    for (int i = 0; i < 4; ++i) {
        v[i] = *(const f32x4*)(src + (size_t)(r0 + tr + 16 * i) * spitch + c0 + tc);
#pragma unroll
        for (int j = 0; j < 4; ++j) v[i][j] *= scale;
    }
    if (dstS) {
#pragma unroll
        for (int i = 0; i < 4; ++i) {
            u16x4 o;
#pragma unroll
            for (int j = 0; j < 4; ++j) o[j] = f2bf(v[i][j]);
            *(u16x4*)(dstS + (size_t)(r0 + tr + 16 * i) * spitch + c0 + tc) = o;
        }
    }
    if (dstT) {
#pragma unroll
        for (int i = 0; i < 4; ++i)
#pragma unroll
            for (int j = 0; j < 4; ++j) tile[(tr + 16 * i) * 65 + tc + j] = v[i][j];
        __syncthreads();
        // dstT has 1024 source-rows per output row (conf is 1024x1024, W is 1024xA)
#pragma unroll
        for (int i = 0; i < 4; ++i) {
            int orow = tr + 16 * i;          // column index in the source tile
            u16x4 o;
#pragma unroll
            for (int j = 0; j < 4; ++j) o[j] = f2bf(tile[(tc + j) * 65 + orow]);
            *(u16x4*)(dstT + (size_t)(c0 + orow) * 1024 + r0 + tc) = o;
        }
    }
}

// ---------------------------------------------------------------------------
// 64x64-tile bf16 MFMA GEMM: C[M,N] (fp32) = A[M,K] (bf16 row-major)
// x Bt[N,K]^T (bf16, B stored transposed so both operands are K-contiguous).
// 4 waves (2x2), each 32x32 out = 2x2 frags of 16x16x32. LDS XOR-swizzled.
// ---------------------------------------------------------------------------
__device__ __forceinline__ void gemm64(
    const short* __restrict__ Ag, const short* __restrict__ Btg,
    float* __restrict__ C, int K, int ldc, int m0, int n0,
    short* As, short* Bs)
{
    const int tid = threadIdx.x;
    const int wid = tid >> 6, lane = tid & 63;
    const int wm = wid >> 1, wn = wid & 1;
    const int lr = lane & 15;            // frag row (A) / col (B)
    const int lk = (lane >> 4) * 8;      // frag k-offset
    const int cr = (lane >> 4) * 4;      // C frag row base

    f32x4 acc[2][2] = {};

    for (int k0 = 0; k0 < K; k0 += 64) {
#pragma unroll
        for (int p = 0; p < 2; ++p) {
            int idx = tid + p * 256;               // 0..511
            int row = idx >> 3, c8 = idx & 7;      // row 0..63, 8-elem chunk
            bf16x8 va = *(const bf16x8*)(Ag  + (size_t)(m0 + row) * K + k0 + c8 * 8);
            bf16x8 vb = *(const bf16x8*)(Btg + (size_t)(n0 + row) * K + k0 + c8 * 8);
            int off = (row * 64 + c8 * 8) ^ ((row & 7) << 3);
            *(bf16x8*)(As + off) = va;
            *(bf16x8*)(Bs + off) = vb;
        }
        __syncthreads();
        bf16x8 af[2][2], bf[2][2];
#pragma unroll
        for (int ks = 0; ks < 2; ++ks)
#pragma unroll
            for (int i = 0; i < 2; ++i) {
                int r = wm * 32 + i * 16 + lr;
                af[i][ks] = *(const bf16x8*)(As + ((r * 64 + ks * 32 + lk) ^ ((r & 7) << 3)));
                int c = wn * 32 + i * 16 + lr;
                bf[i][ks] = *(const bf16x8*)(Bs + ((c * 64 + ks * 32 + lk) ^ ((c & 7) << 3)));
            }
#pragma unroll
        for (int ks = 0; ks < 2; ++ks)
#pragma unroll
            for (int am = 0; am < 2; ++am)
#pragma unroll
                for (int bn = 0; bn < 2; ++bn)
                    acc[am][bn] = __builtin_amdgcn_mfma_f32_16x16x32_bf16(
                        af[am][ks], bf[bn][ks], acc[am][bn], 0, 0, 0);
        __syncthreads();
    }
#pragma unroll
    for (int am = 0; am < 2; ++am)
#pragma unroll
        for (int bn = 0; bn < 2; ++bn) {
            float* cp = C + (size_t)(m0 + wm * 32 + am * 16 + cr) * ldc
                          + n0 + wn * 32 + bn * 16 + lr;
#pragma unroll
            for (int r = 0; r < 4; ++r) cp[(size_t)r * ldc] = acc[am][bn][r];
        }
}

// Kernel 1: q' = fuse_bf @ WqT^T, k' = conf_bf @ WkT^T (both prescaled via W).
__global__ __launch_bounds__(256) void qk_gemm_kernel(
    const short* __restrict__ fuse_bf, const short* __restrict__ conf_bf,
    const short* __restrict__ WqT, const short* __restrict__ WkT,
    float* __restrict__ qbuf, float* __restrict__ kbuf)
{
    __shared__ short As[64 * 64];
    __shared__ short Bs[64 * 64];
    int bid = blockIdx.x;
    if (bid < 32) {       // q: M=512 -> 8 x 4 tiles
        gemm64(fuse_bf, WqT, qbuf, FUSE, A, (bid >> 2) * 64, (bid & 3) * 64, As, Bs);
    } else {              // k: M=1024 -> 16 x 4 tiles
        bid -= 32;
        gemm64(conf_bf, WkT, kbuf, D, A, (bid >> 2) * 64, (bid & 3) * 64, As, Bs);
    }
}

// Kernel 4: fin = w_bf @ confT^T
__global__ __launch_bounds__(256) void fin_gemm_kernel(
    const short* __restrict__ wb, const short* __restrict__ confT,
    float* __restrict__ out)
{
    __shared__ short As[64 * 64];
    __shared__ short Bs[64 * 64];
    gemm64(wb, confT, out, N, D, blockIdx.y * 64, blockIdx.x * 64, As, Bs);
}

// ---------------------------------------------------------------------------
// Kernel 2: s[b,n] = -2 * sum_a wt[a] * rcp(exp2(q'[b,a]+k'[n,a]) + 1)
// (softmax-shift-equivalent to sum_a wt[a]*tanh(q+k))
// ---------------------------------------------------------------------------
__global__ __launch_bounds__(256) void scores_kernel(
    const float* __restrict__ qbuf, const float* __restrict__ kbuf,
    const float* __restrict__ wt, float* __restrict__ s)
{
    __shared__ f32x4 qs[32 * 64];
    __shared__ f32x4 ks[32 * 64];
    const int tid = threadIdx.x;
    const int b0 = blockIdx.x * 32;
    const int n0 = blockIdx.y * 32;

    const f32x4* q4 = (const f32x4*)qbuf + (size_t)b0 * 64;
    const f32x4* k4 = (const f32x4*)kbuf + (size_t)n0 * 64;
#pragma unroll
    for (int j = 0; j < 8; ++j) {
        int idx = tid + j * 256;
        int r = idx >> 6, c = idx & 63;
        qs[idx] = q4[idx];
        ks[r * 64 + (c ^ (r & 15))] = k4[idx];
    }
    __syncthreads();

    const int bl = tid >> 5;   // 0..7
    const int nl = tid & 31;   // 0..31
    const f32x4* wt4 = (const f32x4*)wt;

    float acc0 = 0.f, acc1 = 0.f, acc2 = 0.f, acc3 = 0.f;
    for (int a4 = 0; a4 < 64; ++a4) {
        f32x4 kv = ks[nl * 64 + (a4 ^ (nl & 15))];
        f32x4 wv = wt4[a4];
        f32x4 q0 = qs[(bl) * 64 + a4];
        f32x4 q1 = qs[(bl + 8) * 64 + a4];
        f32x4 q2 = qs[(bl + 16) * 64 + a4];
        f32x4 q3 = qs[(bl + 24) * 64 + a4];
#pragma unroll
        for (int c = 0; c < 4; ++c) {
            float kc = kv[c], wc = wv[c];
            acc0 += wc * fast_rcp(fast_exp2(q0[c] + kc) + 1.0f);
            acc1 += wc * fast_rcp(fast_exp2(q1[c] + kc) + 1.0f);
            acc2 += wc * fast_rcp(fast_exp2(q2[c] + kc) + 1.0f);
            acc3 += wc * fast_rcp(fast_exp2(q3[c] + kc) + 1.0f);
        }
    }
    s[(size_t)(b0 + bl) * N + n0 + nl]      = -2.0f * acc0;
    s[(size_t)(b0 + bl + 8) * N + n0 + nl]  = -2.0f * acc1;
    s[(size_t)(b0 + bl + 16) * N + n0 + nl] = -2.0f * acc2;
    s[(size_t)(b0 + bl + 24) * N + n0 + nl] = -2.0f * acc3;
}

// ---------------------------------------------------------------------------
// Kernel 3: row softmax over N, times probs[n]; emit bf16 attn weights.
// ---------------------------------------------------------------------------
__global__ __launch_bounds__(256) void softmax_kernel(
    const float* __restrict__ s, const float* __restrict__ probs,
    short* __restrict__ wbuf)
{
    const int b = blockIdx.x, tid = threadIdx.x;
    const f32x4* s4 = (const f32x4*)(s + (size_t)b * N);
    f32x4 v = s4[tid];

    float m = fmaxf(fmaxf(v[0], v[1]), fmaxf(v[2], v[3]));
    for (int off = 32; off > 0; off >>= 1) m = fmaxf(m, __shfl_xor(m, off));
    __shared__ float redm[4];
    __shared__ float reds[4];
    const int wid = tid >> 6, lane = tid & 63;
    if (lane == 0) redm[wid] = m;
    __syncthreads();
    m = fmaxf(fmaxf(redm[0], redm[1]), fmaxf(redm[2], redm[3]));

    f32x4 e;
#pragma unroll
    for (int c = 0; c < 4; ++c) e[c] = fast_exp2((v[c] - m) * LOG2E);
    float sum = e[0] + e[1] + e[2] + e[3];
    for (int off = 32; off > 0; off >>= 1) sum += __shfl_xor(sum, off);
    if (lane == 0) reds[wid] = sum;
    __syncthreads();
    sum = reds[0] + reds[1] + reds[2] + reds[3];

    const float inv = fast_rcp(sum);
    const f32x4* p4 = (const f32x4*)probs;
    f32x4 p = p4[tid];
    u16x4 o;
#pragma unroll
    for (int c = 0; c < 4; ++c) o[c] = f2bf(e[c] * inv * p[c]);
    ((u16x4*)(wbuf + (size_t)b * N))[tid] = o;
}

// ---------------------------------------------------------------------------
extern "C" void kernel_launch(void* const* d_in, const int* in_sizes, int n_in,
                              void* d_out, int out_size, void* d_ws, size_t ws_size,
                              hipStream_t stream) {
    const float* conf     = (const float*)d_in[0]; // [N,D]
    const float* fuse_rep = (const float*)d_in[1]; // [B,FUSE]
    const float* probs    = (const float*)d_in[2]; // [1,N]
    const float* Wq       = (const float*)d_in[3]; // [FUSE,A]
    const float* Wk       = (const float*)d_in[4]; // [D,A]
    const float* wt       = (const float*)d_in[5]; // [A]
    float* out = (float*)d_out;                    // [B,D]

    char* w = (char*)d_ws;
    float* qbuf   = (float*)(w);                    //  512 KB  [0, 512K)
    float* kbuf   = (float*)(w + 524288);           //    1 MB  [512K, 1.5M)
    float* sbuf   = (float*)(w + 1572864);          //    2 MB  [1.5M, 3.5M)
    short* fuse_bf= (short*)(w + 3670016);          //    1 MB
    short* conf_bf= (short*)(w + 4718592);          //    2 MB
    short* confT  = (short*)(w + 6815744);          //    2 MB
    short* WqT    = (short*)(w + 8912896);          //  512 KB
    short* WkT    = (short*)(w + 9437184);          //  512 KB  (end ~9.5 MB)
    short* wbuf   = (short*)(w);                    // 1 MB, aliases qbuf/kbuf (free after scores)

    hipLaunchKernelGGL(cast_kernel, dim3(512), dim3(256), 0, stream,
                       fuse_rep, conf, Wq, Wk, fuse_bf, conf_bf, confT, WqT, WkT);
    hipLaunchKernelGGL(qk_gemm_kernel, dim3(96), dim3(256), 0, stream,
                       fuse_bf, conf_bf, WqT, WkT, qbuf, kbuf);
    hipLaunchKernelGGL(scores_kernel, dim3(B / 32, N / 32), dim3(256), 0, stream,
                       qbuf, kbuf, wt, sbuf);
    hipLaunchKernelGGL(softmax_kernel, dim3(B), dim3(256), 0, stream,
                       sbuf, probs, wbuf);
    hipLaunchKernelGGL(fin_gemm_kernel, dim3(D / 64, B / 64), dim3(256), 0, stream,
                       wbuf, confT, out);
}